// Round 4
// baseline (106.108 us; speedup 1.0000x reference)
//
#include <hip/hip_runtime.h>
#include <math.h>

#define Bb 4
#define Cc 256
#define Hh 128
#define Ww 128
#define HW (Hh * Ww)
#define Kk 9

typedef float f32x2 __attribute__((ext_vector_type(2)));

// ---------------------------------------------------------------------------
// Kernel 1: D[b][k][p] = sum_c x[b][c][p] * w[c*9 + k]
// grid = 512 blocks x 512 threads (8 waves) -> 2 blocks/CU, 16 waves/CU.
// Wave wv owns channels [wv*32, wv*32+32); each thread owns 2 consecutive
// pixels loaded as one dwordx2 (f32x2). Inner loop uses v_pk_fma_f32
// (packed 2-wide f32 FMA) to halve VALU issue: 9 pk_fma per channel.
// ---------------------------------------------------------------------------
__global__ __launch_bounds__(512) void proj_kernel(const float* __restrict__ x,
                                                   const float* __restrict__ w,
                                                   float* __restrict__ D) {
    const int tid   = threadIdx.x;
    const int lane  = tid & 63;
    const int wv    = tid >> 6;            // 0..7
    const int bid   = blockIdx.x;          // 0..511
    const int b     = bid >> 7;            // 128 blocks per batch image
    const int pbase = (bid & 127) << 7;    // 128 pixels per block
    const int p2    = pbase + lane * 2;    // this thread's first pixel

    // wave-uniform channel chunk -> weight addresses become s_loads
    const int cu = __builtin_amdgcn_readfirstlane(wv);
    const float* __restrict__ wp = w + cu * 32 * Kk;
    const float* __restrict__ xp = x + (size_t)(b * Cc + cu * 32) * HW + p2;

    f32x2 acc[Kk];
#pragma unroll
    for (int k = 0; k < Kk; ++k) acc[k] = (f32x2)(0.f, 0.f);

#pragma unroll 8
    for (int ci = 0; ci < 32; ++ci) {
        const f32x2 xv = *reinterpret_cast<const f32x2*>(xp + (size_t)ci * HW);
#pragma unroll
        for (int k = 0; k < Kk; ++k) {
            const float wk = wp[ci * Kk + k];
            acc[k] = __builtin_elementwise_fma(xv, (f32x2)(wk, wk), acc[k]);
        }
    }

    // Two-phase cross-wave reduction: waves 0-3 write, waves 4-7 accumulate.
    __shared__ float red[4][128][Kk];      // 18.4 KB
    if (wv < 4) {
#pragma unroll
        for (int j = 0; j < 2; ++j)
#pragma unroll
            for (int k = 0; k < Kk; ++k) red[wv][lane * 2 + j][k] = acc[k][j];
    }
    __syncthreads();
    if (wv >= 4) {
#pragma unroll
        for (int j = 0; j < 2; ++j)
#pragma unroll
            for (int k = 0; k < Kk; ++k) red[wv - 4][lane * 2 + j][k] += acc[k][j];
    }
    __syncthreads();

    // 1152 outputs (128 px x 9 taps); idx = k*128 + px -> coalesced D writes.
    for (int idx = tid; idx < 128 * Kk; idx += 512) {
        const int k  = idx >> 7;
        const int px = idx & 127;
        const float s = red[0][px][k] + red[1][px][k] + red[2][px][k] + red[3][px][k];
        D[(b * Kk + k) * HW + pbase + px] = s;
    }
}

// ---------------------------------------------------------------------------
// Kernel 2: bilinear-sample the 9 projected planes, reduce, sigmoid.
// grid = 1024 blocks x 192 threads (3 waves). Block covers 64 pixels;
// wave ktrio handles taps {3*ktrio, 3*ktrio+1, 3*ktrio+2}.
// ---------------------------------------------------------------------------
__global__ __launch_bounds__(192) void sample_kernel(const float* __restrict__ off,
                                                     const float* __restrict__ D,
                                                     const float* __restrict__ bias,
                                                     float* __restrict__ out) {
    const int tid   = threadIdx.x;         // 0..191
    const int lane  = tid & 63;
    const int ktrio = tid >> 6;            // 0..2
    const int bid   = blockIdx.x;          // 0..1023
    const int b     = bid >> 8;            // 256 blocks per batch image
    const int p     = ((bid & 255) << 6) + lane;
    const int h     = p >> 7;
    const int w_    = p & (Ww - 1);

    const float* __restrict__ offb = off + (size_t)b * (2 * Kk) * HW + p;
    const float* __restrict__ Db   = D + (size_t)b * Kk * HW;

    float s = 0.f;

#pragma unroll
    for (int j = 0; j < 3; ++j) {
        const int k = ktrio * 3 + j;
        const float dy = offb[(size_t)(2 * k) * HW];
        const float dx = offb[(size_t)(2 * k + 1) * HW];
        const float y  = (float)(h - 1 + ktrio) + dy;   // ky == ktrio
        const float xq = (float)(w_ - 1 + j) + dx;      // kx == j

        const float y0f = floorf(y);
        const float x0f = floorf(xq);
        const float wy  = y - y0f;
        const float wx  = xq - x0f;
        const int y0 = (int)y0f;
        const int x0 = (int)x0f;

        const float* __restrict__ Dk = Db + k * HW;

        {
            const int yy = y0, xx = x0;
            const bool valid = (yy >= 0) & (yy < Hh) & (xx >= 0) & (xx < Ww);
            const int yi = min(max(yy, 0), Hh - 1);
            const int xi = min(max(xx, 0), Ww - 1);
            const float v = Dk[yi * Ww + xi];
            s += valid ? (1.f - wy) * (1.f - wx) * v : 0.f;
        }
        {
            const int yy = y0, xx = x0 + 1;
            const bool valid = (yy >= 0) & (yy < Hh) & (xx >= 0) & (xx < Ww);
            const int yi = min(max(yy, 0), Hh - 1);
            const int xi = min(max(xx, 0), Ww - 1);
            const float v = Dk[yi * Ww + xi];
            s += valid ? (1.f - wy) * wx * v : 0.f;
        }
        {
            const int yy = y0 + 1, xx = x0;
            const bool valid = (yy >= 0) & (yy < Hh) & (xx >= 0) & (xx < Ww);
            const int yi = min(max(yy, 0), Hh - 1);
            const int xi = min(max(xx, 0), Ww - 1);
            const float v = Dk[yi * Ww + xi];
            s += valid ? wy * (1.f - wx) * v : 0.f;
        }
        {
            const int yy = y0 + 1, xx = x0 + 1;
            const bool valid = (yy >= 0) & (yy < Hh) & (xx >= 0) & (xx < Ww);
            const int yi = min(max(yy, 0), Hh - 1);
            const int xi = min(max(xx, 0), Ww - 1);
            const float v = Dk[yi * Ww + xi];
            s += valid ? wy * wx * v : 0.f;
        }
    }

    __shared__ float part[3][64];
    part[ktrio][lane] = s;
    __syncthreads();

    if (tid < 64) {
        const float t = part[0][lane] + part[1][lane] + part[2][lane] + bias[0];
        out[(b << 14) + ((bid & 255) << 6) + lane] = 1.f / (1.f + expf(-t));
    }
}

extern "C" void kernel_launch(void* const* d_in, const int* in_sizes, int n_in,
                              void* d_out, int out_size, void* d_ws, size_t ws_size,
                              hipStream_t stream) {
    const float* x    = (const float*)d_in[0];  // [4,256,128,128]
    const float* off  = (const float*)d_in[1];  // [4,18,128,128]
    const float* w    = (const float*)d_in[2];  // [1,256,3,3]
    const float* bias = (const float*)d_in[3];  // [1]
    float* out        = (float*)d_out;          // [4,1,128,128]

    float* D = (float*)d_ws;  // [4][9][16384] f32 = 2.25 MB scratch

    proj_kernel<<<512, 512, 0, stream>>>(x, w, D);
    sample_kernel<<<1024, 192, 0, stream>>>(off, D, bias, out);
}

// Round 5
// 105.520 us; speedup vs baseline: 1.0056x; 1.0056x over previous
//
#include <hip/hip_runtime.h>
#include <math.h>

#define Bb 4
#define Cc 256
#define Hh 128
#define Ww 128
#define HW (Hh * Ww)
#define Kk 9

typedef float f32x2 __attribute__((ext_vector_type(2)));

// ---------------------------------------------------------------------------
// Kernel 1: D[b][k][p] = sum_c x[b][c][p] * w[c*9 + k]
// grid = 512 blocks x 1024 threads (16 waves) -> 2 blocks/CU, 32 waves/CU
// (8 waves/SIMD — max occupancy at <=64 VGPR, forced via launch_bounds).
// Wave wv owns channels [wv*16, wv*16+16); each thread owns 2 consecutive
// pixels (one float2 / dwordx2 load, 512B per wave-instruction).
// Two-phase LDS reduction: waves 0-7 store, waves 8-15 accumulate,
// then 8 partials summed at the end. LDS = 36.9 KB (2 blocks co-resident).
// ---------------------------------------------------------------------------
__global__ __launch_bounds__(1024, 8) void proj_kernel(const float* __restrict__ x,
                                                       const float* __restrict__ w,
                                                       float* __restrict__ D) {
    const int tid   = threadIdx.x;
    const int lane  = tid & 63;
    const int wv    = tid >> 6;            // 0..15
    const int bid   = blockIdx.x;          // 0..511
    const int b     = bid >> 7;            // 128 blocks per batch image
    const int pbase = (bid & 127) << 7;    // 128 pixels per block
    const int p2    = pbase + lane * 2;    // this thread's first pixel

    // wave-uniform channel chunk -> weight addresses become s_loads
    const int cu = __builtin_amdgcn_readfirstlane(wv);
    const float* __restrict__ wp = w + cu * 16 * Kk;
    const float* __restrict__ xp = x + (size_t)(b * Cc + cu * 16) * HW + p2;

    f32x2 acc[Kk];
#pragma unroll
    for (int k = 0; k < Kk; ++k) acc[k] = (f32x2)(0.f, 0.f);

#pragma unroll 4
    for (int ci = 0; ci < 16; ++ci) {
        const f32x2 xv = *reinterpret_cast<const f32x2*>(xp + (size_t)ci * HW);
#pragma unroll
        for (int k = 0; k < Kk; ++k) {
            const float wk = wp[ci * Kk + k];
            acc[k] = __builtin_elementwise_fma(xv, (f32x2)(wk, wk), acc[k]);
        }
    }

    // Two-phase cross-wave reduction: waves 0-7 store, waves 8-15 accumulate.
    __shared__ f32x2 red[8][64][Kk];       // 36,864 B
    if (wv < 8) {
#pragma unroll
        for (int k = 0; k < Kk; ++k) red[wv][lane][k] = acc[k];
    }
    __syncthreads();
    if (wv >= 8) {
#pragma unroll
        for (int k = 0; k < Kk; ++k) red[wv - 8][lane][k] += acc[k];
    }
    __syncthreads();

    // 1152 outputs (128 px x 9 taps); idx = k*128 + px -> coalesced D writes.
    const float* __restrict__ redf = (const float*)red;
    for (int idx = tid; idx < 128 * Kk; idx += 1024) {
        const int k  = idx >> 7;
        const int px = idx & 127;
        const int base = (((px >> 1) * Kk + k) << 1) + (px & 1);
        float s = 0.f;
#pragma unroll
        for (int g = 0; g < 8; ++g) s += redf[g * (64 * Kk * 2) + base];
        D[(b * Kk + k) * HW + pbase + px] = s;
    }
}

// ---------------------------------------------------------------------------
// Kernel 2: bilinear-sample the 9 projected planes, reduce, sigmoid.
// grid = 1024 blocks x 192 threads (3 waves). Block covers 64 pixels;
// wave ktrio handles taps {3*ktrio, 3*ktrio+1, 3*ktrio+2}.
// ---------------------------------------------------------------------------
__global__ __launch_bounds__(192) void sample_kernel(const float* __restrict__ off,
                                                     const float* __restrict__ D,
                                                     const float* __restrict__ bias,
                                                     float* __restrict__ out) {
    const int tid   = threadIdx.x;         // 0..191
    const int lane  = tid & 63;
    const int ktrio = tid >> 6;            // 0..2
    const int bid   = blockIdx.x;          // 0..1023
    const int b     = bid >> 8;            // 256 blocks per batch image
    const int p     = ((bid & 255) << 6) + lane;
    const int h     = p >> 7;
    const int w_    = p & (Ww - 1);

    const float* __restrict__ offb = off + (size_t)b * (2 * Kk) * HW + p;
    const float* __restrict__ Db   = D + (size_t)b * Kk * HW;

    float s = 0.f;

#pragma unroll
    for (int j = 0; j < 3; ++j) {
        const int k = ktrio * 3 + j;
        const float dy = offb[(size_t)(2 * k) * HW];
        const float dx = offb[(size_t)(2 * k + 1) * HW];
        const float y  = (float)(h - 1 + ktrio) + dy;   // ky == ktrio
        const float xq = (float)(w_ - 1 + j) + dx;      // kx == j

        const float y0f = floorf(y);
        const float x0f = floorf(xq);
        const float wy  = y - y0f;
        const float wx  = xq - x0f;
        const int y0 = (int)y0f;
        const int x0 = (int)x0f;

        const float* __restrict__ Dk = Db + k * HW;

        {
            const int yy = y0, xx = x0;
            const bool valid = (yy >= 0) & (yy < Hh) & (xx >= 0) & (xx < Ww);
            const int yi = min(max(yy, 0), Hh - 1);
            const int xi = min(max(xx, 0), Ww - 1);
            const float v = Dk[yi * Ww + xi];
            s += valid ? (1.f - wy) * (1.f - wx) * v : 0.f;
        }
        {
            const int yy = y0, xx = x0 + 1;
            const bool valid = (yy >= 0) & (yy < Hh) & (xx >= 0) & (xx < Ww);
            const int yi = min(max(yy, 0), Hh - 1);
            const int xi = min(max(xx, 0), Ww - 1);
            const float v = Dk[yi * Ww + xi];
            s += valid ? (1.f - wy) * wx * v : 0.f;
        }
        {
            const int yy = y0 + 1, xx = x0;
            const bool valid = (yy >= 0) & (yy < Hh) & (xx >= 0) & (xx < Ww);
            const int yi = min(max(yy, 0), Hh - 1);
            const int xi = min(max(xx, 0), Ww - 1);
            const float v = Dk[yi * Ww + xi];
            s += valid ? wy * (1.f - wx) * v : 0.f;
        }
        {
            const int yy = y0 + 1, xx = x0 + 1;
            const bool valid = (yy >= 0) & (yy < Hh) & (xx >= 0) & (xx < Ww);
            const int yi = min(max(yy, 0), Hh - 1);
            const int xi = min(max(xx, 0), Ww - 1);
            const float v = Dk[yi * Ww + xi];
            s += valid ? wy * wx * v : 0.f;
        }
    }

    __shared__ float part[3][64];
    part[ktrio][lane] = s;
    __syncthreads();

    if (tid < 64) {
        const float t = part[0][lane] + part[1][lane] + part[2][lane] + bias[0];
        out[(b << 14) + ((bid & 255) << 6) + lane] = 1.f / (1.f + expf(-t));
    }
}

extern "C" void kernel_launch(void* const* d_in, const int* in_sizes, int n_in,
                              void* d_out, int out_size, void* d_ws, size_t ws_size,
                              hipStream_t stream) {
    const float* x    = (const float*)d_in[0];  // [4,256,128,128]
    const float* off  = (const float*)d_in[1];  // [4,18,128,128]
    const float* w    = (const float*)d_in[2];  // [1,256,3,3]
    const float* bias = (const float*)d_in[3];  // [1]
    float* out        = (float*)d_out;          // [4,1,128,128]

    float* D = (float*)d_ws;  // [4][9][16384] f32 = 2.25 MB scratch

    proj_kernel<<<512, 1024, 0, stream>>>(x, w, D);
    sample_kernel<<<1024, 192, 0, stream>>>(off, D, bias, out);
}

// Round 6
// 103.125 us; speedup vs baseline: 1.0289x; 1.0232x over previous
//
#include <hip/hip_runtime.h>
#include <math.h>

#define Bb 4
#define Cc 256
#define Hh 128
#define Ww 128
#define HW (Hh * Ww)
#define Kk 9

typedef float f32x4 __attribute__((ext_vector_type(4)));

// ---------------------------------------------------------------------------
// Kernel 1: D[b][k][p] = sum_c x[b][c][p] * w[c*9 + k]
// grid = 256 blocks x 1024 threads (16 waves) -> 1 block/CU, 16 waves/CU.
// Wave wv owns channels [wv*16, wv*16+16); each lane owns 4 consecutive
// pixels via one dwordx4 load (1 KB contiguous per wave-instruction --
// double R5's 512 B granule, same stream count per CU).
// Two-phase LDS reduction (16 -> 8 -> sum of 8). LDS = 72 KB (1 block/CU).
// ---------------------------------------------------------------------------
__global__ __launch_bounds__(1024, 4) void proj_kernel(const float* __restrict__ x,
                                                       const float* __restrict__ w,
                                                       float* __restrict__ D) {
    const int tid   = threadIdx.x;
    const int lane  = tid & 63;
    const int wv    = tid >> 6;            // 0..15
    const int bid   = blockIdx.x;          // 0..255
    const int b     = bid >> 6;            // 64 blocks per batch image
    const int pbase = (bid & 63) << 8;     // 256 pixels per block
    const int p4    = pbase + lane * 4;    // this lane's first pixel

    // wave-uniform channel chunk -> weight addresses become s_loads
    const int cu = __builtin_amdgcn_readfirstlane(wv);
    const float* __restrict__ wp = w + cu * 16 * Kk;
    const float* __restrict__ xp = x + (size_t)(b * Cc + cu * 16) * HW + p4;

    f32x4 acc[Kk];
#pragma unroll
    for (int k = 0; k < Kk; ++k) acc[k] = (f32x4)(0.f);

#pragma unroll 4
    for (int ci = 0; ci < 16; ++ci) {
        const f32x4 xv = *reinterpret_cast<const f32x4*>(xp + (size_t)ci * HW);
#pragma unroll
        for (int k = 0; k < Kk; ++k) {
            const float wk = wp[ci * Kk + k];
            acc[k] = __builtin_elementwise_fma(xv, (f32x4)(wk), acc[k]);
        }
    }

    // Two-phase cross-wave reduction: waves 0-7 store, waves 8-15 accumulate.
    __shared__ f32x4 red[8][64][Kk];       // 73,728 B
    if (wv < 8) {
#pragma unroll
        for (int k = 0; k < Kk; ++k) red[wv][lane][k] = acc[k];
    }
    __syncthreads();
    if (wv >= 8) {
#pragma unroll
        for (int k = 0; k < Kk; ++k) red[wv - 8][lane][k] += acc[k];
    }
    __syncthreads();

    // 2304 outputs (256 px x 9 taps); idx = k*256 + px -> coalesced D writes.
    const float* __restrict__ redf = (const float*)red;
    for (int idx = tid; idx < 256 * Kk; idx += 1024) {
        const int k  = idx >> 8;
        const int px = idx & 255;
        const int base = (px >> 2) * (Kk * 4) + k * 4 + (px & 3);
        float s = 0.f;
#pragma unroll
        for (int g = 0; g < 8; ++g) s += redf[g * (64 * Kk * 4) + base];
        D[(b * Kk + k) * HW + pbase + px] = s;
    }
}

// ---------------------------------------------------------------------------
// Kernel 2: bilinear-sample the 9 projected planes, reduce, sigmoid.
// grid = 512 blocks x 512 threads (8 waves) -> 2 blocks/CU, 16 waves/CU.
// Block owns 128 pixels; tap-group g = tid>>7 (wave-uniform) handles
// taps {g, g+4} (+ tap 8 for g==0). ky/kx are compile-time per tap.
// ---------------------------------------------------------------------------
__global__ __launch_bounds__(512) void sample_kernel(const float* __restrict__ off,
                                                     const float* __restrict__ D,
                                                     const float* __restrict__ bias,
                                                     float* __restrict__ out) {
    const int tid   = threadIdx.x;         // 0..511
    const int px    = tid & 127;
    const int g     = tid >> 7;            // 0..3, wave-uniform
    const int bid   = blockIdx.x;          // 0..511
    const int b     = bid >> 7;            // 128 blocks per batch image
    const int pbase = (bid & 127) << 7;    // 128 pixels per block
    const int p     = pbase + px;
    const int h     = p >> 7;
    const int w_    = p & (Ww - 1);

    const float* __restrict__ offb = off + (size_t)b * (2 * Kk) * HW + p;
    const float* __restrict__ Db   = D + (size_t)b * Kk * HW;

    float s = 0.f;

#define TAP(K)                                                                 \
    do {                                                                       \
        constexpr int kk = (K);                                                \
        constexpr int ky = kk / 3, kx = kk % 3;                                \
        const float dy = offb[(size_t)(2 * kk) * HW];                          \
        const float dx = offb[(size_t)(2 * kk + 1) * HW];                      \
        const float y  = (float)(h - 1 + ky) + dy;                             \
        const float xq = (float)(w_ - 1 + kx) + dx;                            \
        const float y0f = floorf(y);                                           \
        const float x0f = floorf(xq);                                          \
        const float wy  = y - y0f;                                             \
        const float wx  = xq - x0f;                                            \
        const int y0 = (int)y0f;                                               \
        const int x0 = (int)x0f;                                               \
        const float* __restrict__ Dk = Db + kk * HW;                           \
        {                                                                      \
            const int yy = y0, xx = x0;                                        \
            const bool valid = (yy >= 0) & (yy < Hh) & (xx >= 0) & (xx < Ww);  \
            const int yi = min(max(yy, 0), Hh - 1);                            \
            const int xi = min(max(xx, 0), Ww - 1);                            \
            const float v = Dk[yi * Ww + xi];                                  \
            s += valid ? (1.f - wy) * (1.f - wx) * v : 0.f;                    \
        }                                                                      \
        {                                                                      \
            const int yy = y0, xx = x0 + 1;                                    \
            const bool valid = (yy >= 0) & (yy < Hh) & (xx >= 0) & (xx < Ww);  \
            const int yi = min(max(yy, 0), Hh - 1);                            \
            const int xi = min(max(xx, 0), Ww - 1);                            \
            const float v = Dk[yi * Ww + xi];                                  \
            s += valid ? (1.f - wy) * wx * v : 0.f;                            \
        }                                                                      \
        {                                                                      \
            const int yy = y0 + 1, xx = x0;                                    \
            const bool valid = (yy >= 0) & (yy < Hh) & (xx >= 0) & (xx < Ww);  \
            const int yi = min(max(yy, 0), Hh - 1);                            \
            const int xi = min(max(xx, 0), Ww - 1);                            \
            const float v = Dk[yi * Ww + xi];                                  \
            s += valid ? wy * (1.f - wx) * v : 0.f;                            \
        }                                                                      \
        {                                                                      \
            const int yy = y0 + 1, xx = x0 + 1;                                \
            const bool valid = (yy >= 0) & (yy < Hh) & (xx >= 0) & (xx < Ww);  \
            const int yi = min(max(yy, 0), Hh - 1);                            \
            const int xi = min(max(xx, 0), Ww - 1);                            \
            const float v = Dk[yi * Ww + xi];                                  \
            s += valid ? wy * wx * v : 0.f;                                    \
        }                                                                      \
    } while (0)

    if (g == 0) {
        TAP(0); TAP(4); TAP(8);
    } else if (g == 1) {
        TAP(1); TAP(5);
    } else if (g == 2) {
        TAP(2); TAP(6);
    } else {
        TAP(3); TAP(7);
    }
#undef TAP

    __shared__ float part[4][128];
    part[g][px] = s;
    __syncthreads();

    if (tid < 128) {
        const float t = part[0][px] + part[1][px] + part[2][px] + part[3][px] + bias[0];
        out[(b << 14) + pbase + px] = 1.f / (1.f + expf(-t));
    }
}

extern "C" void kernel_launch(void* const* d_in, const int* in_sizes, int n_in,
                              void* d_out, int out_size, void* d_ws, size_t ws_size,
                              hipStream_t stream) {
    const float* x    = (const float*)d_in[0];  // [4,256,128,128]
    const float* off  = (const float*)d_in[1];  // [4,18,128,128]
    const float* w    = (const float*)d_in[2];  // [1,256,3,3]
    const float* bias = (const float*)d_in[3];  // [1]
    float* out        = (float*)d_out;          // [4,1,128,128]

    float* D = (float*)d_ws;  // [4][9][16384] f32 = 2.25 MB scratch

    proj_kernel<<<256, 1024, 0, stream>>>(x, w, D);
    sample_kernel<<<512, 512, 0, stream>>>(off, D, bias, out);
}